// Round 5
// baseline (389.310 us; speedup 1.0000x reference)
//
#include <hip/hip_runtime.h>
#include <hip/hip_bf16.h>
#include <stdint.h>

// Head: B=16, T=2048, C=1024, H=128. out fp32 [B,T,H].
// ws: WtB bf16 [32][384][32]          (Wt tiled: WtB[k/32][n][k%32])
//   | QT  bf16 [16][128][4][16][32]   (Q tiled: [b][t/16][d/32][t%16][d%32])
//   | KT  bf16 [16][128][4][16][32]
//   | VT2 bf16 [16][8][64][16][32]    (V^T tiled: [b][d/16][kv/32][d%16][kv%32])

typedef __bf16 bf16x8 __attribute__((ext_vector_type(8)));
typedef __bf16 bf16x4 __attribute__((ext_vector_type(4)));
typedef float  f32x4  __attribute__((ext_vector_type(4)));
typedef uint32_t u32;

#define MFMA16(a, b, c) __builtin_amdgcn_mfma_f32_16x16x32_bf16((a), (b), (c), 0, 0, 0)
#define LOG2E 1.4426950408889634f

static __device__ __forceinline__ float exp2fast(float x) { return __builtin_exp2f(x); }

static __device__ __forceinline__ bf16x4 pack4(float4 a) {
  bf16x4 r;
  r[0] = (__bf16)a.x; r[1] = (__bf16)a.y; r[2] = (__bf16)a.z; r[3] = (__bf16)a.w;
  return r;
}

static __device__ __forceinline__ u32 pkbf16(float a, float b) {
  union { __bf16 h[2]; u32 u; } t;
  t.h[0] = (__bf16)a; t.h[1] = (__bf16)b;
  return t.u;
}

// ---------- WtB[c>>5][n][c&31] = W_{n/128}[c][n%128] (Wq scaled) ----------
__global__ __launch_bounds__(256) void k_build_wt(
    const float* __restrict__ Wq, const float* __restrict__ Wk,
    const float* __restrict__ Wv, __bf16* __restrict__ WtB)
{
  __shared__ float tile[32][33];
  const int tx = threadIdx.x, ty = threadIdx.y;
  const int c0 = blockIdx.x * 32, h0 = blockIdx.y * 32, w = blockIdx.z;
  const float* W = (w == 0) ? Wq : (w == 1) ? Wk : Wv;
  const float s = (w == 0) ? 0.08838834764831843f : 1.0f;
#pragma unroll
  for (int i = 0; i < 4; ++i)
    tile[ty + i * 8][tx] = W[(size_t)(c0 + ty + i * 8) * 128 + h0 + tx];
  __syncthreads();
#pragma unroll
  for (int i = 0; i < 4; ++i) {
    const int n = w * 128 + h0 + ty + i * 8;
    WtB[(size_t)blockIdx.x * 12288 + (size_t)n * 32 + tx] =
        (__bf16)(tile[tx][ty + i * 8] * s);
  }
}

// ---------- fused QKV projection: BM=64, BK=32, all 384 N-cols, 8 waves ----------
__global__ __launch_bounds__(512, 4) void k_proj(
    const float* __restrict__ x, const __bf16* __restrict__ WtB,
    __bf16* __restrict__ QT, __bf16* __restrict__ KT, __bf16* __restrict__ VT2)
{
  const int tid  = threadIdx.x;
  const int lane = tid & 63, wid = tid >> 6;
  const int lr = lane & 15, g = lane >> 4;
  const int m0 = blockIdx.x * 64;

  __shared__ __bf16 As[2][64][32];

  const int srow = tid >> 3;
  const int sc4  = (tid & 7) * 4;
  char* AsB = (char*)As;
  const int wbyte = (srow * 64 + sc4 * 2) ^ (((srow >> 1) & 3) << 4);
  const float* xrow = x + (size_t)(m0 + srow) * 1024 + sc4;

  const int nbase = wid * 48;
  const __bf16* wB = WtB + (size_t)(nbase + lr) * 32 + g * 8;

  f32x4 acc[4][3] = {};

  float4 xreg = *(const float4*)(xrow);
  bf16x8 bcur[3], bnext[3];
#pragma unroll
  for (int j = 0; j < 3; ++j)
    bcur[j] = *(const bf16x8*)(wB + (size_t)j * 512);

  for (int kt = 0; kt < 32; ++kt) {
    const int buf = kt & 1;
    *(bf16x4*)(AsB + buf * 4096 + wbyte) = pack4(xreg);
    if (kt < 31)
      xreg = *(const float4*)(xrow + (kt + 1) * 32);
    asm volatile("s_waitcnt lgkmcnt(0)\n\ts_barrier" ::: "memory");

    bf16x8 af[4];
#pragma unroll
    for (int i = 0; i < 4; ++i) {
      const int row = i * 16 + lr;
      af[i] = *(const bf16x8*)(AsB + buf * 4096 +
                               (row * 64 + ((g * 16) ^ (((row >> 1) & 3) << 4))));
    }
    if (kt < 31) {
      const __bf16* wn = wB + (size_t)(kt + 1) * 12288;
#pragma unroll
      for (int j = 0; j < 3; ++j)
        bnext[j] = *(const bf16x8*)(wn + (size_t)j * 512);
    }
#pragma unroll
    for (int j = 0; j < 3; ++j)
#pragma unroll
      for (int i = 0; i < 4; ++i)
        acc[i][j] = MFMA16(af[i], bcur[j], acc[i][j]);
#pragma unroll
    for (int j = 0; j < 3; ++j) bcur[j] = bnext[j];
  }

  const int b = m0 >> 11;
#pragma unroll
  for (int j = 0; j < 3; ++j) {
    const int n = nbase + j * 16 + lr;
#pragma unroll
    for (int i = 0; i < 4; ++i) {
      const int m = m0 + i * 16 + g * 4;
      const int tt = m & 2047;
#pragma unroll
      for (int rr = 0; rr < 4; ++rr) {
        const float v = acc[i][j][rr];
        if (n < 128) {
          QT[(size_t)b * 262144 + (size_t)((tt + rr) >> 4) * 2048 +
             (n >> 5) * 512 + ((tt + rr) & 15) * 32 + (n & 31)] = (__bf16)v;
        } else if (n < 256) {
          const int nk = n - 128;
          KT[(size_t)b * 262144 + (size_t)((tt + rr) >> 4) * 2048 +
             (nk >> 5) * 512 + ((tt + rr) & 15) * 32 + (nk & 31)] = (__bf16)v;
        } else {
          const int d = n - 256, kv = tt + rr;
          VT2[(size_t)b * 262144 + (size_t)(d >> 4) * 32768 +
              (kv >> 5) * 512 + (d & 15) * 32 + (kv & 31)] = (__bf16)v;
        }
      }
    }
  }
}

// ---------- causal flash attention ----------
// Flat grid; b = flat&15 -> all blocks of a batch pin to XCD b%8 (K/V L2-resident).
// Block = 16 q-rows; 4 waves split 32-kv tiles round-robin; two-pass fp32 combine.
__global__ __launch_bounds__(256, 4) void k_attn(
    const __bf16* __restrict__ QT, const __bf16* __restrict__ KT,
    const __bf16* __restrict__ VT2, float* __restrict__ out)
{
  const int tid  = threadIdx.x;
  const int lane = tid & 63, wid = tid >> 6;
  const int lr = lane & 15, g = lane >> 4;
  const int flat = blockIdx.x;
  const int b    = flat & 15;          // XCD = b % 8 (round-robin dispatch)
  const int qblk = flat >> 4;          // 0..127
  const int q0   = (127 - qblk) << 4;  // heavy blocks first

  __shared__ float Lo[4][16][68];      // reused in two 64-col passes
  __shared__ float Lml[4][16][2];

  const __bf16* QTb = QT  + (size_t)b * 262144;
  const __bf16* KTb = KT  + (size_t)b * 262144;
  const __bf16* VTb = VT2 + (size_t)b * 262144;
  const int fo = lr * 32 + g * 8;

  bf16x8 qf[4];
#pragma unroll
  for (int d4 = 0; d4 < 4; ++d4)
    qf[d4] = *(const bf16x8*)(QTb + (size_t)(q0 >> 4) * 2048 + d4 * 512 + fo);

  f32x4 o[8] = {};
  float m = -1e30f, l = 0.0f;

  const int ntiles = (q0 >> 5) + 1;
  bf16x8 kf0[4], kf1[4];
  if (wid < ntiles) {
    const __bf16* kp = KTb + (size_t)wid * 4096 + fo;
#pragma unroll
    for (int d4 = 0; d4 < 4; ++d4) {
      kf0[d4] = *(const bf16x8*)(kp + d4 * 512);
      kf1[d4] = *(const bf16x8*)(kp + 2048 + d4 * 512);
    }
  }

  for (int t = wid; t < ntiles; t += 4) {
    const int kv0 = t << 5;
    bf16x8 vf[8];
#pragma unroll
    for (int dt = 0; dt < 8; ++dt)
      vf[dt] = *(const bf16x8*)(VTb + (size_t)dt * 32768 + (size_t)(kv0 >> 5) * 512 + fo);
    bf16x8 kf0n[4], kf1n[4];
    const int tn = t + 4;
    if (tn < ntiles) {
      const __bf16* kp = KTb + (size_t)tn * 4096 + fo;
#pragma unroll
      for (int d4 = 0; d4 < 4; ++d4) {
        kf0n[d4] = *(const bf16x8*)(kp + d4 * 512);
        kf1n[d4] = *(const bf16x8*)(kp + 2048 + d4 * 512);
      }
    }

    f32x4 s0 = {}, s1 = {};
    __builtin_amdgcn_s_setprio(1);
#pragma unroll
    for (int d4 = 0; d4 < 4; ++d4) {
      s0 = MFMA16(kf0[d4], qf[d4], s0);   // lane: q=q0+lr, kv=kv0+g*4+rr
      s1 = MFMA16(kf1[d4], qf[d4], s1);   // kv=kv0+16+g*4+rr
    }
    __builtin_amdgcn_s_setprio(0);

    if (kv0 + 31 > q0) {                  // diagonal tile: causal mask
      const int qrow = q0 + lr;
#pragma unroll
      for (int rr = 0; rr < 4; ++rr) {
        if (kv0 + g * 4 + rr > qrow)      s0[rr] = -1e30f;
        if (kv0 + 16 + g * 4 + rr > qrow) s1[rr] = -1e30f;
      }
    }
    float mx = fmaxf(fmaxf(fmaxf(s0[0], s0[1]), fmaxf(s0[2], s0[3])),
                     fmaxf(fmaxf(s1[0], s1[1]), fmaxf(s1[2], s1[3])));
    mx = fmaxf(mx, __shfl_xor(mx, 16));
    mx = fmaxf(mx, __shfl_xor(mx, 32));

    float al = 1.0f;
    if (!__all(mx <= m)) {               // T13 defer-max: rescale only on max growth
      const float mnew = fmaxf(m, mx);
      al = exp2fast((m - mnew) * LOG2E);
      m = mnew;
#pragma unroll
      for (int dt = 0; dt < 8; ++dt) {
#pragma unroll
        for (int rr = 0; rr < 4; ++rr) o[dt][rr] *= al;
      }
    }
    float p[8];
#pragma unroll
    for (int rr = 0; rr < 4; ++rr) {
      p[rr]     = exp2fast((s0[rr] - m) * LOG2E);
      p[4 + rr] = exp2fast((s1[rr] - m) * LOG2E);
    }
    float ps = ((p[0] + p[1]) + (p[2] + p[3])) + ((p[4] + p[5]) + (p[6] + p[7]));
    ps += __shfl_xor(ps, 16);
    ps += __shfl_xor(ps, 32);
    l = l * al + ps;

    // P^T B-frag redistribution: publish all 4 packed words, select lo/hi at target.
    const u32 c0 = pkbf16(p[0], p[1]), c1 = pkbf16(p[2], p[3]);
    const u32 c2 = pkbf16(p[4], p[5]), c3 = pkbf16(p[6], p[7]);
    const int srcA = (lr + ((g & 1) << 5)) << 2;
    const u32 lo0 = (u32)__builtin_amdgcn_ds_bpermute(srcA,      (int)c0);
    const u32 lo1 = (u32)__builtin_amdgcn_ds_bpermute(srcA,      (int)c1);
    const u32 hi0 = (u32)__builtin_amdgcn_ds_bpermute(srcA,      (int)c2);
    const u32 hi1 = (u32)__builtin_amdgcn_ds_bpermute(srcA,      (int)c3);
    const u32 lo2 = (u32)__builtin_amdgcn_ds_bpermute(srcA + 64, (int)c0);
    const u32 lo3 = (u32)__builtin_amdgcn_ds_bpermute(srcA + 64, (int)c1);
    const u32 hi2 = (u32)__builtin_amdgcn_ds_bpermute(srcA + 64, (int)c2);
    const u32 hi3 = (u32)__builtin_amdgcn_ds_bpermute(srcA + 64, (int)c3);
    const bool hi = (g & 2) != 0;
    union { u32 u[4]; bf16x8 v; } pu;
    pu.u[0] = hi ? hi0 : lo0;
    pu.u[1] = hi ? hi1 : lo1;
    pu.u[2] = hi ? hi2 : lo2;
    pu.u[3] = hi ? hi3 : lo3;
    const bf16x8 pb = pu.v;

    __builtin_amdgcn_s_setprio(1);
#pragma unroll
    for (int dt = 0; dt < 8; ++dt)
      o[dt] = MFMA16(vf[dt], pb, o[dt]);
    __builtin_amdgcn_s_setprio(0);

#pragma unroll
    for (int d4 = 0; d4 < 4; ++d4) { kf0[d4] = kf0n[d4]; kf1[d4] = kf1n[d4]; }
  }

  // two-pass fp32 combine (17.9 KB LDS)
  if (lane < 16) { Lml[wid][lr][0] = m; Lml[wid][lr][1] = l; }
#pragma unroll
  for (int dt = 0; dt < 4; ++dt)
    *(f32x4*)&Lo[wid][lr][dt * 16 + g * 4] = o[dt];
  __syncthreads();

  const int row = tid >> 4, cg = tid & 15;
  float mw[4], lw[4];
#pragma unroll
  for (int w = 0; w < 4; ++w) { mw[w] = Lml[w][row][0]; lw[w] = Lml[w][row][1]; }
  const float M = fmaxf(fmaxf(mw[0], mw[1]), fmaxf(mw[2], mw[3]));
  float wt[4], L = 0.0f;
#pragma unroll
  for (int w = 0; w < 4; ++w) { wt[w] = exp2fast((mw[w] - M) * LOG2E); L += lw[w] * wt[w]; }
  const float inv = 1.0f / L;
  float* orow = out + ((size_t)b * 2048 + q0 + row) * 128 + cg * 4;

  f32x4 a0 = {};
#pragma unroll
  for (int w = 0; w < 4; ++w)
    a0 += (*(const f32x4*)&Lo[w][row][cg * 4]) * wt[w];
  *(f32x4*)orow = a0 * inv;
  __syncthreads();                       // all reads of pass 1 done

#pragma unroll
  for (int dt = 4; dt < 8; ++dt)
    *(f32x4*)&Lo[wid][lr][(dt - 4) * 16 + g * 4] = o[dt];
  __syncthreads();

  f32x4 a1 = {};
#pragma unroll
  for (int w = 0; w < 4; ++w)
    a1 += (*(const f32x4*)&Lo[w][row][cg * 4]) * wt[w];
  *(f32x4*)(orow + 64) = a1 * inv;
}

extern "C" void kernel_launch(void* const* d_in, const int* in_sizes, int n_in,
                              void* d_out, int out_size, void* d_ws, size_t ws_size,
                              hipStream_t stream) {
  const float* x  = (const float*)d_in[0];
  const float* Wq = (const float*)d_in[1];
  const float* Wk = (const float*)d_in[2];
  const float* Wv = (const float*)d_in[3];
  float* out = (float*)d_out;

  char* ws = (char*)d_ws;
  __bf16* WtB = (__bf16*)(ws);
  __bf16* QT  = (__bf16*)(ws + 786432);
  __bf16* KT  = (__bf16*)(ws + 9175040);
  __bf16* VT2 = (__bf16*)(ws + 17563648);

  k_build_wt<<<dim3(32, 4, 3), dim3(32, 8), 0, stream>>>(Wq, Wk, Wv, WtB);
  k_proj    <<<dim3(512),      dim3(512),   0, stream>>>(x, WtB, QT, KT, VT2);
  k_attn    <<<dim3(2048),     dim3(256),   0, stream>>>(QT, KT, VT2, out);
}